// Round 1
// baseline (854.212 us; speedup 1.0000x reference)
//
#include <hip/hip_runtime.h>
#include <hip/hip_bf16.h>

#define DIMC 1024
#define NHEAD 16
#define HDIM 64
#define SEQ 2048
#define BATCH 2
#define NCOL 3072  // 3*DIMC

// ---------------------------------------------------------------------------
// Kernel 1: qkv = x @ w_qkv + b_qkv, written as qkv_ws[3][B][H][N][D] (fp32)
// 128x128 tile, K-step 16, 256 threads, 8x8 micro-tile per thread.
// ---------------------------------------------------------------------------
__global__ __launch_bounds__(256) void qkv_gemm(const float* __restrict__ X,
                                                const float* __restrict__ W,
                                                const float* __restrict__ Bias,
                                                float* __restrict__ QKV) {
    __shared__ float As[16][132];  // k-major (transposed A tile)
    __shared__ float Bs[16][132];

    const int t = threadIdx.x;
    const int n0 = blockIdx.x * 128;
    const int m0 = blockIdx.y * 128;

    float acc[8][8];
#pragma unroll
    for (int i = 0; i < 8; ++i)
#pragma unroll
        for (int j = 0; j < 8; ++j) acc[i][j] = 0.f;

    const int rt = (t >> 4) * 8;
    const int ct = (t & 15) * 8;

    for (int k0 = 0; k0 < DIMC; k0 += 16) {
        // stage A: 128 rows x 16 k -> As[k][m]
#pragma unroll
        for (int i = 0; i < 2; ++i) {
            const int a = t + i * 256;       // 0..511 float4 ids
            const int row = a >> 2;          // 0..127
            const int kk = (a & 3) * 4;
            const float4 v =
                *(const float4*)&X[(size_t)(m0 + row) * DIMC + k0 + kk];
            As[kk + 0][row] = v.x;
            As[kk + 1][row] = v.y;
            As[kk + 2][row] = v.z;
            As[kk + 3][row] = v.w;
        }
        // stage B: 16 k x 128 cols -> Bs[k][n]
#pragma unroll
        for (int i = 0; i < 2; ++i) {
            const int bq = t + i * 256;
            const int krow = bq >> 5;        // 0..15
            const int col = (bq & 31) * 4;
            *(float4*)&Bs[krow][col] =
                *(const float4*)&W[(size_t)(k0 + krow) * NCOL + n0 + col];
        }
        __syncthreads();

#pragma unroll
        for (int kk = 0; kk < 16; ++kk) {
            float a8[8], b8[8];
            *(float4*)&a8[0] = *(const float4*)&As[kk][rt];
            *(float4*)&a8[4] = *(const float4*)&As[kk][rt + 4];
            *(float4*)&b8[0] = *(const float4*)&Bs[kk][ct];
            *(float4*)&b8[4] = *(const float4*)&Bs[kk][ct + 4];
#pragma unroll
            for (int i = 0; i < 8; ++i)
#pragma unroll
                for (int j = 0; j < 8; ++j)
                    acc[i][j] = fmaf(a8[i], b8[j], acc[i][j]);
        }
        __syncthreads();
    }

    // epilogue: +bias, scatter into [which][b][h][n][d]
#pragma unroll
    for (int i = 0; i < 8; ++i) {
        const int m = m0 + rt + i;
        const int bb = m >> 11;       // /2048
        const int n = m & 2047;
#pragma unroll
        for (int g = 0; g < 2; ++g) {
            const int j0 = n0 + ct + g * 4;
            const int which = j0 >> 10;
            const int h = (j0 & 1023) >> 6;
            const int d0 = j0 & 63;
            const float4 bias4 = *(const float4*)&Bias[j0];
            float4 o;
            o.x = acc[i][g * 4 + 0] + bias4.x;
            o.y = acc[i][g * 4 + 1] + bias4.y;
            o.z = acc[i][g * 4 + 2] + bias4.z;
            o.w = acc[i][g * 4 + 3] + bias4.w;
            const size_t off =
                ((size_t)((which * BATCH + bb) * NHEAD + h) * SEQ + n) * HDIM +
                d0;
            *(float4*)&QKV[off] = o;
        }
    }
}

// ---------------------------------------------------------------------------
// Kernel 2: flash attention, fp32. One block = (b, h, 64-row q tile).
// 256 threads; online softmax with width-16 shuffle reductions.
// ---------------------------------------------------------------------------
__global__ __launch_bounds__(256) void attn_fwd(const float* __restrict__ QKV,
                                                float* __restrict__ Out) {
    __shared__ float QsT[64][68];  // [d][row]
    __shared__ float KsT[64][68];  // [d][col]
    __shared__ float Vs[64][68];   // [col][d]
    __shared__ float PsT[64][72];  // [col][row]

    const int t = threadIdx.x;
    const int qt = blockIdx.x & 31;
    const int bh = blockIdx.x >> 5;
    const int b = bh >> 4, h = bh & 15;

    const size_t plane = (size_t)SEQ * HDIM;
    const float* Q = QKV + ((size_t)(0 * BATCH + b) * NHEAD + h) * plane;
    const float* K = QKV + ((size_t)(1 * BATCH + b) * NHEAD + h) * plane;
    const float* V = QKV + ((size_t)(2 * BATCH + b) * NHEAD + h) * plane;

    // stage Q transposed (once)
    {
        const int r = t >> 2;
        const int dstart = (t & 3) * 16;
#pragma unroll
        for (int i = 0; i < 4; ++i) {
            const float4 v =
                *(const float4*)&Q[(size_t)(qt * 64 + r) * HDIM + dstart + i * 4];
            QsT[dstart + i * 4 + 0][r] = v.x;
            QsT[dstart + i * 4 + 1][r] = v.y;
            QsT[dstart + i * 4 + 2][r] = v.z;
            QsT[dstart + i * 4 + 3][r] = v.w;
        }
    }

    const int rt = (t >> 4) * 4;   // q-row group (shared by 16 lanes)
    const int ct = (t & 15) * 4;   // key-col group / d-col group

    float m_i[4], l_i[4], acc[4][4];
#pragma unroll
    for (int i = 0; i < 4; ++i) {
        m_i[i] = -1e30f;
        l_i[i] = 0.f;
#pragma unroll
        for (int j = 0; j < 4; ++j) acc[i][j] = 0.f;
    }

    for (int c0 = 0; c0 < SEQ; c0 += 64) {
        __syncthreads();  // protect Ks/Vs/PsT from previous iteration readers
        // stage K^T and V for this tile
        {
            const int r = t >> 2;
            const int dstart = (t & 3) * 16;
#pragma unroll
            for (int i = 0; i < 4; ++i) {
                const float4 kv =
                    *(const float4*)&K[(size_t)(c0 + r) * HDIM + dstart + i * 4];
                KsT[dstart + i * 4 + 0][r] = kv.x;
                KsT[dstart + i * 4 + 1][r] = kv.y;
                KsT[dstart + i * 4 + 2][r] = kv.z;
                KsT[dstart + i * 4 + 3][r] = kv.w;
                const float4 vv =
                    *(const float4*)&V[(size_t)(c0 + r) * HDIM + dstart + i * 4];
                *(float4*)&Vs[r][dstart + i * 4] = vv;
            }
        }
        __syncthreads();

        // S = (Q K^T) * scale  -- 4x4 micro-tile per thread
        float s[4][4];
#pragma unroll
        for (int i = 0; i < 4; ++i)
#pragma unroll
            for (int j = 0; j < 4; ++j) s[i][j] = 0.f;

#pragma unroll 8
        for (int d = 0; d < 64; ++d) {
            const float4 q4 = *(const float4*)&QsT[d][rt];
            const float4 k4 = *(const float4*)&KsT[d][ct];
            const float qa[4] = {q4.x, q4.y, q4.z, q4.w};
            const float ka[4] = {k4.x, k4.y, k4.z, k4.w};
#pragma unroll
            for (int i = 0; i < 4; ++i)
#pragma unroll
                for (int j = 0; j < 4; ++j)
                    s[i][j] = fmaf(qa[i], ka[j], s[i][j]);
        }

        // online softmax update (rows shared across 16-lane groups)
#pragma unroll
        for (int i = 0; i < 4; ++i) {
#pragma unroll
            for (int j = 0; j < 4; ++j) s[i][j] *= 0.125f;  // HEAD_DIM^-0.5
            float mx = fmaxf(fmaxf(s[i][0], s[i][1]), fmaxf(s[i][2], s[i][3]));
#pragma unroll
            for (int o = 8; o >= 1; o >>= 1) mx = fmaxf(mx, __shfl_xor(mx, o, 16));
            const float mnew = fmaxf(m_i[i], mx);
            const float rescale = __expf(m_i[i] - mnew);
            float rs = 0.f;
#pragma unroll
            for (int j = 0; j < 4; ++j) {
                s[i][j] = __expf(s[i][j] - mnew);
                rs += s[i][j];
            }
#pragma unroll
            for (int o = 8; o >= 1; o >>= 1) rs += __shfl_xor(rs, o, 16);
            l_i[i] = l_i[i] * rescale + rs;
            m_i[i] = mnew;
#pragma unroll
            for (int j = 0; j < 4; ++j) acc[i][j] *= rescale;
        }

        // write P transposed for the PV pass
#pragma unroll
        for (int i = 0; i < 4; ++i)
#pragma unroll
            for (int j = 0; j < 4; ++j) PsT[ct + j][rt + i] = s[i][j];
        __syncthreads();

        // acc += P @ V   (rows rt.., d-cols ct..)
#pragma unroll 8
        for (int c = 0; c < 64; ++c) {
            const float4 p4 = *(const float4*)&PsT[c][rt];
            const float4 v4 = *(const float4*)&Vs[c][ct];
            const float pa[4] = {p4.x, p4.y, p4.z, p4.w};
            const float va[4] = {v4.x, v4.y, v4.z, v4.w};
#pragma unroll
            for (int i = 0; i < 4; ++i)
#pragma unroll
                for (int j = 0; j < 4; ++j)
                    acc[i][j] = fmaf(pa[i], va[j], acc[i][j]);
        }
    }

    // epilogue: out[b][n][h*64 + d] = acc / l
#pragma unroll
    for (int i = 0; i < 4; ++i) {
        const float inv = 1.f / l_i[i];
        const int n = qt * 64 + rt + i;
        float4 o;
        o.x = acc[i][0] * inv;
        o.y = acc[i][1] * inv;
        o.z = acc[i][2] * inv;
        o.w = acc[i][3] * inv;
        *(float4*)&Out[((size_t)b * SEQ + n) * DIMC + h * HDIM + ct] = o;
    }
}

extern "C" void kernel_launch(void* const* d_in, const int* in_sizes, int n_in,
                              void* d_out, int out_size, void* d_ws,
                              size_t ws_size, hipStream_t stream) {
    const float* x = (const float*)d_in[0];
    const float* w = (const float*)d_in[1];
    const float* bias = (const float*)d_in[2];
    float* out = (float*)d_out;
    float* qkv = (float*)d_ws;  // 3*2*16*2048*64 floats = 50.3 MB

    dim3 gemm_grid(NCOL / 128, (BATCH * SEQ) / 128);  // 24 x 32
    qkv_gemm<<<gemm_grid, 256, 0, stream>>>(x, w, bias, qkv);

    attn_fwd<<<BATCH * NHEAD * (SEQ / 64), 256, 0, stream>>>(qkv, out);
}

// Round 2
// 175.388 us; speedup vs baseline: 4.8704x; 4.8704x over previous
//
#include <hip/hip_runtime.h>
#include <hip/hip_bf16.h>
#include <stdint.h>

#define DIMC 1024
#define NHEAD 16
#define HDIM 64
#define SEQ 2048
#define BATCH 2
#define NCOL 3072

typedef __attribute__((ext_vector_type(8))) short short8;
typedef __attribute__((ext_vector_type(4))) float f32x4;
typedef __attribute__((ext_vector_type(16))) float f32x16;

__device__ __forceinline__ unsigned short f2b(float f) {
    __hip_bfloat16 h = __float2bfloat16(f);
    return __builtin_bit_cast(unsigned short, h);
}

#define GLL16(src, dst)                                                                  \
    __builtin_amdgcn_global_load_lds(                                                    \
        (const __attribute__((address_space(1))) unsigned int*)(src),                    \
        (__attribute__((address_space(3))) unsigned int*)(dst), 16, 0, 0)

// ---------------------------------------------------------------------------
// x (fp32) -> xb (bf16), 8 elements/thread
// ---------------------------------------------------------------------------
__global__ __launch_bounds__(256) void cvt_x_kernel(const float* __restrict__ X,
                                                    unsigned short* __restrict__ Xb) {
    const int i = blockIdx.x * 256 + threadIdx.x;
    const float4 a = ((const float4*)X)[2 * i];
    const float4 b = ((const float4*)X)[2 * i + 1];
    uint4 o;
    o.x = (unsigned int)f2b(a.x) | ((unsigned int)f2b(a.y) << 16);
    o.y = (unsigned int)f2b(a.z) | ((unsigned int)f2b(a.w) << 16);
    o.z = (unsigned int)f2b(b.x) | ((unsigned int)f2b(b.y) << 16);
    o.w = (unsigned int)f2b(b.z) | ((unsigned int)f2b(b.w) << 16);
    ((uint4*)Xb)[i] = o;
}

// ---------------------------------------------------------------------------
// w[k][n] (fp32) -> wT[n][k] (bf16), 32x32 LDS tiles
// ---------------------------------------------------------------------------
__global__ __launch_bounds__(256) void cvt_w_kernel(const float* __restrict__ W,
                                                    unsigned short* __restrict__ Wt) {
    __shared__ float tile[32][33];
    const int k0 = blockIdx.x * 32, n0 = blockIdx.y * 32;
    const int r = threadIdx.x >> 3, c4 = (threadIdx.x & 7) * 4;
    *(float4*)&tile[r][c4] = *(const float4*)&W[(size_t)(k0 + r) * NCOL + n0 + c4];
    __syncthreads();
    uint2 o;
    o.x = (unsigned int)f2b(tile[c4 + 0][r]) | ((unsigned int)f2b(tile[c4 + 1][r]) << 16);
    o.y = (unsigned int)f2b(tile[c4 + 2][r]) | ((unsigned int)f2b(tile[c4 + 3][r]) << 16);
    *(uint2*)&Wt[(size_t)(n0 + r) * DIMC + k0 + c4] = o;
}

// ---------------------------------------------------------------------------
// qkv = xb @ wT^T + bias -> bf16 [which][b][h][n][d]
// 128x128 tile, BK=64, 4 waves, 16x16x32 bf16 MFMA, swizzled LDS,
// global_load_lds(16B) with pre-swizzled source.
// ---------------------------------------------------------------------------
__global__ __launch_bounds__(256) void qkv_gemm(const unsigned short* __restrict__ Xb,
                                                const unsigned short* __restrict__ Wt,
                                                const float* __restrict__ Bias,
                                                unsigned short* __restrict__ QKV) {
    __shared__ short Al[128 * 64];  // [m][k], 16B-slot s stored at s ^ (m&7)
    __shared__ short Bl[128 * 64];  // [n][k]
    const int t = threadIdx.x;
    const int lane = t & 63;
    const int w = t >> 6;
    const int m0 = blockIdx.y * 128, n0 = blockIdx.x * 128;
    const int wr = w >> 1, wc = w & 1;

    f32x4 acc[4][4];
#pragma unroll
    for (int i = 0; i < 4; ++i)
#pragma unroll
        for (int j = 0; j < 4; ++j)
#pragma unroll
            for (int e = 0; e < 4; ++e) acc[i][j][e] = 0.f;

    const int srow = lane >> 3;              // row within 8-row chunk
    const int sslot = (lane & 7) ^ srow;     // pre-swizzled source 16B slot

    for (int k0 = 0; k0 < DIMC; k0 += 64) {
        __syncthreads();
#pragma unroll
        for (int i = 0; i < 4; ++i) {
            const int row = w * 32 + i * 8;
            GLL16(Xb + (size_t)(m0 + row + srow) * DIMC + k0 + sslot * 8, &Al[row * 64]);
            GLL16(Wt + (size_t)(n0 + row + srow) * DIMC + k0 + sslot * 8, &Bl[row * 64]);
        }
        __syncthreads();
#pragma unroll
        for (int kb = 0; kb < 2; ++kb) {
            short8 af[4], bfr[4];
#pragma unroll
            for (int rf = 0; rf < 4; ++rf) {
                const int mloc = wr * 64 + rf * 16 + (lane & 15);
                const int slot = (4 * kb + (lane >> 4)) ^ (mloc & 7);
                af[rf] = *(const short8*)&Al[mloc * 64 + slot * 8];
            }
#pragma unroll
            for (int cf = 0; cf < 4; ++cf) {
                const int nloc = wc * 64 + cf * 16 + (lane & 15);
                const int slot = (4 * kb + (lane >> 4)) ^ (nloc & 7);
                bfr[cf] = *(const short8*)&Bl[nloc * 64 + slot * 8];
            }
#pragma unroll
            for (int rf = 0; rf < 4; ++rf)
#pragma unroll
                for (int cf = 0; cf < 4; ++cf)
                    acc[rf][cf] = __builtin_amdgcn_mfma_f32_16x16x32_bf16(
                        af[rf], bfr[cf], acc[rf][cf], 0, 0, 0);
        }
    }

    float bias_c[4];
    int j0_c[4];
#pragma unroll
    for (int cf = 0; cf < 4; ++cf) {
        j0_c[cf] = n0 + wc * 64 + cf * 16 + (lane & 15);
        bias_c[cf] = Bias[j0_c[cf]];
    }
#pragma unroll
    for (int rf = 0; rf < 4; ++rf) {
#pragma unroll
        for (int r = 0; r < 4; ++r) {
            const int m = m0 + wr * 64 + rf * 16 + (lane >> 4) * 4 + r;
            const int bb = m >> 11, nn = m & (SEQ - 1);
#pragma unroll
            for (int cf = 0; cf < 4; ++cf) {
                const int j0 = j0_c[cf];
                const int which = j0 >> 10, h = (j0 >> 6) & 15, d = j0 & 63;
                QKV[(size_t)(((which * BATCH + bb) * NHEAD + h) * SEQ + nn) * HDIM + d] =
                    f2b(acc[rf][cf][r] + bias_c[cf]);
            }
        }
    }
}

// ---------------------------------------------------------------------------
// Flash attention, bf16 MFMA 32x32x16. Block = (b, h, 128 q-rows), 4 waves,
// wave = 32 q-rows. S^T = K*Q^T so softmax is per-lane over 32 regs + 1 shfl.
// ---------------------------------------------------------------------------
__global__ __launch_bounds__(256) void attn_fwd(const unsigned short* __restrict__ QKV,
                                                float* __restrict__ Out) {
    __shared__ short Kl[64 * 64];      // [kv][d], slot s at s ^ (kv&7)
    __shared__ short Vt[64 * 64];      // [d][kv], elem k at k ^ ((d&7)<<3)
    __shared__ short Pl[4][32 * 64];   // per-wave [q][kv], elem k at k ^ ((q&7)<<3)

    const int t = threadIdx.x;
    const int lane = t & 63;
    const int w = t >> 6;
    const int hi = lane >> 5;
    const int q5 = lane & 31;

    const int qt = blockIdx.x & 15;
    const int bh = blockIdx.x >> 4;
    const int b = bh >> 4, h = bh & 15;

    const size_t plane = (size_t)SEQ * HDIM;
    const unsigned short* Qg = QKV + ((size_t)(0 * BATCH + b) * NHEAD + h) * plane;
    const unsigned short* Kg = QKV + ((size_t)(1 * BATCH + b) * NHEAD + h) * plane;
    const unsigned short* Vg = QKV + ((size_t)(2 * BATCH + b) * NHEAD + h) * plane;

    // Q fragment (B operand of S^T): col=q5, k = ks*16 + hi*8 + j
    const int qrow = qt * 128 + w * 32 + q5;
    short8 qf[4];
#pragma unroll
    for (int ks = 0; ks < 4; ++ks)
        qf[ks] = *(const short8*)&Qg[(size_t)qrow * HDIM + ks * 16 + hi * 8];

    f32x16 oacc0, oacc1;
#pragma unroll
    for (int e = 0; e < 16; ++e) { oacc0[e] = 0.f; oacc1[e] = 0.f; }
    float m_i = -1e30f, l_i = 0.f;

    const int srow = lane >> 3;
    const int sslot = (lane & 7) ^ srow;
    const int vn = t & 31, vdg = t >> 5;

    for (int c0 = 0; c0 < SEQ; c0 += 64) {
        __syncthreads();
        // stage K rows (global_load_lds, pre-swizzled source)
#pragma unroll
        for (int i = 0; i < 2; ++i) {
            const int row = w * 16 + i * 8;
            GLL16(Kg + (size_t)(c0 + row + srow) * HDIM + sslot * 8, &Kl[row * 64]);
        }
        // stage V transposed: n-major lanes for conflict-balanced scatter
#pragma unroll
        for (int it = 0; it < 2; ++it) {
            const int n = vn + it * 32;
            const short8 vv = *(const short8*)&Vg[(size_t)(c0 + n) * HDIM + vdg * 8];
#pragma unroll
            for (int j = 0; j < 8; ++j)
                Vt[(vdg * 8 + j) * 64 + (n ^ (j << 3))] = vv[j];
        }
        __syncthreads();

        // S^T = K * Q^T (rows kv, cols q)
        f32x16 s0, s1;
#pragma unroll
        for (int e = 0; e < 16; ++e) { s0[e] = 0.f; s1[e] = 0.f; }
#pragma unroll
        for (int ks = 0; ks < 4; ++ks) {
            const int slot = ((2 * ks + hi) ^ (q5 & 7)) * 8;
            const short8 k0f = *(const short8*)&Kl[q5 * 64 + slot];
            const short8 k1f = *(const short8*)&Kl[(32 + q5) * 64 + slot];
            s0 = __builtin_amdgcn_mfma_f32_32x32x16_bf16(k0f, qf[ks], s0, 0, 0, 0);
            s1 = __builtin_amdgcn_mfma_f32_32x32x16_bf16(k1f, qf[ks], s1, 0, 0, 0);
        }

        // online softmax: lane owns q-col q5, 32 kv values (lane^32 has the other 32)
        float mx = s0[0];
#pragma unroll
        for (int e = 1; e < 16; ++e) mx = fmaxf(mx, s0[e]);
#pragma unroll
        for (int e = 0; e < 16; ++e) mx = fmaxf(mx, s1[e]);
        mx = fmaxf(mx, __shfl_xor(mx, 32, 64));
        const float mnew = fmaxf(m_i, mx * 0.125f);
        const float resc = __expf(m_i - mnew);
        m_i = mnew;

        // rescale O (rows of oacc are q = (reg&3)+8*(reg>>2)+4*hi; resc lives at lane q)
#pragma unroll
        for (int reg = 0; reg < 16; ++reg) {
            const int row = (reg & 3) + 8 * (reg >> 2) + 4 * hi;
            const float rr = __shfl(resc, row, 64);
            oacc0[reg] *= rr;
            oacc1[reg] *= rr;
        }

        // P = exp(S*scale - m), write to Pl[w][q][kv] (swizzled), accumulate row-sum
        float ls = 0.f;
#pragma unroll
        for (int g = 0; g < 8; ++g) {
            const int kvsub = g >> 2, rg = g & 3;
            unsigned int pw[2];
#pragma unroll
            for (int half = 0; half < 2; ++half) {
                float pe0, pe1;
                if (kvsub == 0) {
                    pe0 = __expf(fmaf(s0[rg * 4 + half * 2 + 0], 0.125f, -mnew));
                    pe1 = __expf(fmaf(s0[rg * 4 + half * 2 + 1], 0.125f, -mnew));
                } else {
                    pe0 = __expf(fmaf(s1[rg * 4 + half * 2 + 0], 0.125f, -mnew));
                    pe1 = __expf(fmaf(s1[rg * 4 + half * 2 + 1], 0.125f, -mnew));
                }
                ls += pe0 + pe1;
                pw[half] = (unsigned int)f2b(pe0) | ((unsigned int)f2b(pe1) << 16);
            }
            const int kv = kvsub * 32 + 8 * rg + 4 * hi;
            uint2 u;
            u.x = pw[0];
            u.y = pw[1];
            *(uint2*)&Pl[w][q5 * 64 + (kv ^ ((q5 & 7) << 3))] = u;
        }
        ls += __shfl_xor(ls, 32, 64);
        l_i = l_i * resc + ls;

        // O += P @ V
#pragma unroll
        for (int ks = 0; ks < 4; ++ks) {
            const int kbase = ks * 16 + hi * 8;
            const int sw = (q5 & 7) << 3;
            const short8 pf = *(const short8*)&Pl[w][q5 * 64 + (kbase ^ sw)];
            const short8 v0f = *(const short8*)&Vt[q5 * 64 + (kbase ^ sw)];
            const short8 v1f = *(const short8*)&Vt[(32 + q5) * 64 + (kbase ^ sw)];
            oacc0 = __builtin_amdgcn_mfma_f32_32x32x16_bf16(pf, v0f, oacc0, 0, 0, 0);
            oacc1 = __builtin_amdgcn_mfma_f32_32x32x16_bf16(pf, v1f, oacc1, 0, 0, 0);
        }
    }

    const float linv = 1.0f / l_i;
#pragma unroll
    for (int reg = 0; reg < 16; ++reg) {
        const int row = (reg & 3) + 8 * (reg >> 2) + 4 * hi;
        const float iv = __shfl(linv, row, 64);
        const int n = qt * 128 + w * 32 + row;
        float* o = Out + ((size_t)b * SEQ + n) * DIMC + h * HDIM;
        o[q5] = oacc0[reg] * iv;
        o[32 + q5] = oacc1[reg] * iv;
    }
}

extern "C" void kernel_launch(void* const* d_in, const int* in_sizes, int n_in,
                              void* d_out, int out_size, void* d_ws, size_t ws_size,
                              hipStream_t stream) {
    const float* x = (const float*)d_in[0];
    const float* wq = (const float*)d_in[1];
    const float* bias = (const float*)d_in[2];
    float* out = (float*)d_out;

    unsigned short* qkv = (unsigned short*)d_ws;                          // 25,165,824 B
    unsigned short* xb = (unsigned short*)((char*)d_ws + 25165824);       // 16,777,216 B
    unsigned short* wT = (unsigned short*)((char*)d_ws + 41943040);       //  6,291,456 B

    cvt_x_kernel<<<BATCH * SEQ * DIMC / 8 / 256, 256, 0, stream>>>(x, xb);
    dim3 wgrid(DIMC / 32, NCOL / 32);
    cvt_w_kernel<<<wgrid, 256, 0, stream>>>(wq, wT);
    dim3 ggrid(NCOL / 128, BATCH * SEQ / 128);
    qkv_gemm<<<ggrid, 256, 0, stream>>>(xb, wT, bias, qkv);
    attn_fwd<<<BATCH * NHEAD * (SEQ / 128), 256, 0, stream>>>(qkv, out);
}

// Round 6
// 130.593 us; speedup vs baseline: 6.5410x; 1.3430x over previous
//
#include <hip/hip_runtime.h>
#include <hip/hip_bf16.h>
#include <stdint.h>

#define DIMC 1024
#define NHEAD 16
#define HDIM 64
#define SEQ 2048
#define BATCH 2
#define NCOL 3072

typedef __attribute__((ext_vector_type(8))) short short8;
typedef __attribute__((ext_vector_type(4))) float f32x4;
typedef __attribute__((ext_vector_type(16))) float f32x16;

__device__ __forceinline__ unsigned short f2b(float f) {
    __hip_bfloat16 h = __float2bfloat16(f);
    return __builtin_bit_cast(unsigned short, h);
}
__device__ __forceinline__ unsigned int pk2(float a, float b) {
    return (unsigned int)f2b(a) | ((unsigned int)f2b(b) << 16);
}

#define GLL16(src, dst)                                                                  \
    __builtin_amdgcn_global_load_lds(                                                    \
        (const __attribute__((address_space(1))) unsigned int*)(src),                    \
        (__attribute__((address_space(3))) unsigned int*)(dst), 16, 0, 0)

// ---------------------------------------------------------------------------
// Fused converts: blocks [0,2048) do x->bf16; blocks [2048,5120) do w->wT bf16
// ---------------------------------------------------------------------------
__global__ __launch_bounds__(256) void cvt_fused(const float* __restrict__ X,
                                                 const float* __restrict__ W,
                                                 unsigned short* __restrict__ Xb,
                                                 unsigned short* __restrict__ Wt) {
    __shared__ float tile[32][33];
    const int bid = blockIdx.x;
    if (bid < 2048) {
        const int i = bid * 256 + threadIdx.x;
        const float4 a = ((const float4*)X)[2 * i];
        const float4 b = ((const float4*)X)[2 * i + 1];
        uint4 o;
        o.x = pk2(a.x, a.y);
        o.y = pk2(a.z, a.w);
        o.z = pk2(b.x, b.y);
        o.w = pk2(b.z, b.w);
        ((uint4*)Xb)[i] = o;
    } else {
        const int b2 = bid - 2048;
        const int k0 = (b2 & 31) * 32, n0 = (b2 >> 5) * 32;
        const int r = threadIdx.x >> 3, c4 = (threadIdx.x & 7) * 4;
        *(float4*)&tile[r][c4] = *(const float4*)&W[(size_t)(k0 + r) * NCOL + n0 + c4];
        __syncthreads();
        uint2 o;
        o.x = pk2(tile[c4 + 0][r], tile[c4 + 1][r]);
        o.y = pk2(tile[c4 + 2][r], tile[c4 + 3][r]);
        *(uint2*)&Wt[(size_t)(n0 + r) * DIMC + k0 + c4] = o;
    }
}

// ---------------------------------------------------------------------------
// qkv GEMM. Q,K written [which][b][h][n][d]; V written TRANSPOSED [b][h][d][n]
// into the V region (offset 2*B*H*N*D), packed 8B stores.
// ---------------------------------------------------------------------------
__global__ __launch_bounds__(256) void qkv_gemm(const unsigned short* __restrict__ Xb,
                                                const unsigned short* __restrict__ Wt,
                                                const float* __restrict__ Bias,
                                                unsigned short* __restrict__ QKV) {
    __shared__ short Al[128 * 64];
    __shared__ short Bl[128 * 64];
    const int t = threadIdx.x;
    const int lane = t & 63;
    const int w = t >> 6;
    const int m0 = blockIdx.y * 128, n0 = blockIdx.x * 128;
    const int wr = w >> 1, wc = w & 1;

    f32x4 acc[4][4];
#pragma unroll
    for (int i = 0; i < 4; ++i)
#pragma unroll
        for (int j = 0; j < 4; ++j)
#pragma unroll
            for (int e = 0; e < 4; ++e) acc[i][j][e] = 0.f;

    const int srow = lane >> 3;
    const int sslot = (lane & 7) ^ srow;

    for (int k0 = 0; k0 < DIMC; k0 += 64) {
        __syncthreads();
#pragma unroll
        for (int i = 0; i < 4; ++i) {
            const int row = w * 32 + i * 8;
            GLL16(Xb + (size_t)(m0 + row + srow) * DIMC + k0 + sslot * 8, &Al[row * 64]);
            GLL16(Wt + (size_t)(n0 + row + srow) * DIMC + k0 + sslot * 8, &Bl[row * 64]);
        }
        __syncthreads();
#pragma unroll
        for (int kb = 0; kb < 2; ++kb) {
            short8 af[4], bfr[4];
#pragma unroll
            for (int rf = 0; rf < 4; ++rf) {
                const int mloc = wr * 64 + rf * 16 + (lane & 15);
                const int slot = (4 * kb + (lane >> 4)) ^ (mloc & 7);
                af[rf] = *(const short8*)&Al[mloc * 64 + slot * 8];
            }
#pragma unroll
            for (int cf = 0; cf < 4; ++cf) {
                const int nloc = wc * 64 + cf * 16 + (lane & 15);
                const int slot = (4 * kb + (lane >> 4)) ^ (nloc & 7);
                bfr[cf] = *(const short8*)&Bl[nloc * 64 + slot * 8];
            }
#pragma unroll
            for (int rf = 0; rf < 4; ++rf)
#pragma unroll
                for (int cf = 0; cf < 4; ++cf)
                    acc[rf][cf] = __builtin_amdgcn_mfma_f32_16x16x32_bf16(
                        af[rf], bfr[cf], acc[rf][cf], 0, 0, 0);
        }
    }

    float bias_c[4];
    int j0_c[4];
#pragma unroll
    for (int cf = 0; cf < 4; ++cf) {
        j0_c[cf] = n0 + wc * 64 + cf * 16 + (lane & 15);
        bias_c[cf] = Bias[j0_c[cf]];
    }

    const int whichU = n0 >> 10;  // uniform per block
    if (whichU < 2) {
        // Q,K: [which][b][h][n][d] scalar stores (proven)
#pragma unroll
        for (int rf = 0; rf < 4; ++rf) {
#pragma unroll
            for (int r = 0; r < 4; ++r) {
                const int m = m0 + wr * 64 + rf * 16 + (lane >> 4) * 4 + r;
                const int bb = m >> 11, nn = m & (SEQ - 1);
#pragma unroll
                for (int cf = 0; cf < 4; ++cf) {
                    const int j0 = j0_c[cf];
                    const int h = (j0 >> 6) & 15, d = j0 & 63;
                    QKV[(size_t)(((whichU * BATCH + bb) * NHEAD + h) * SEQ + nn) * HDIM +
                        d] = f2b(acc[rf][cf][r] + bias_c[cf]);
                }
            }
        }
    } else {
        // V: transposed [b][h][d][n], 4 consecutive n packed into one 8B store
        const int bb = m0 >> 11;
        const size_t vbase = (size_t)2 * BATCH * NHEAD * SEQ * HDIM;
#pragma unroll
        for (int rf = 0; rf < 4; ++rf) {
            const int nn = (m0 & (SEQ - 1)) + wr * 64 + rf * 16 + (lane >> 4) * 4;
#pragma unroll
            for (int cf = 0; cf < 4; ++cf) {
                const int j0 = j0_c[cf];
                const int h = (j0 >> 6) & 15, d = j0 & 63;
                uint2 u;
                u.x = pk2(acc[rf][cf][0] + bias_c[cf], acc[rf][cf][1] + bias_c[cf]);
                u.y = pk2(acc[rf][cf][2] + bias_c[cf], acc[rf][cf][3] + bias_c[cf]);
                *(uint2*)&QKV[vbase + (((size_t)bb * NHEAD + h) * HDIM + d) * SEQ + nn] = u;
            }
        }
    }
}

// ---------------------------------------------------------------------------
// Flash attention v3: round-2 structure (proven layouts) + V^T staging via
// GLL16 (no scalar scatter), double-buffered tiles, defer-max, exp2 domain.
// ---------------------------------------------------------------------------
__global__ __launch_bounds__(256) void attn_fwd(const unsigned short* __restrict__ QKV,
                                                float* __restrict__ Out) {
    __shared__ short Kl[2][64 * 64];   // [kv][d], slot s of row r holds global slot s^rs(r)
    __shared__ short Vl[2][64 * 64];   // [d][kv], same swizzle
    __shared__ short Pl[4][32 * 72];   // per-wave [q][kv], stride 72, group^(q>>3)

    const int t = threadIdx.x;
    const int lane = t & 63;
    const int w = t >> 6;
    const int hi = lane >> 5;
    const int q5 = lane & 31;

    const int qt = blockIdx.x & 15;
    const int bh = blockIdx.x >> 4;
    const int b = bh >> 4, h = bh & 15;

    const size_t plane = (size_t)SEQ * HDIM;
    const unsigned short* Qg = QKV + ((size_t)(0 * BATCH + b) * NHEAD + h) * plane;
    const unsigned short* Kg = QKV + ((size_t)(1 * BATCH + b) * NHEAD + h) * plane;
    const unsigned short* Vtg =
        QKV + (size_t)2 * BATCH * NHEAD * plane + ((size_t)(b * NHEAD + h)) * plane;

    // Q fragment (B operand of S^T = K*Q^T): col=q5, k = ks*16 + hi*8 + j
    const int qrow = qt * 128 + w * 32 + q5;
    short8 qf[4];
#pragma unroll
    for (int ks = 0; ks < 4; ++ks)
        qf[ks] = *(const short8*)&Qg[(size_t)qrow * HDIM + ks * 16 + hi * 8];

    f32x16 oacc0, oacc1;
#pragma unroll
    for (int e = 0; e < 16; ++e) { oacc0[e] = 0.f; oacc1[e] = 0.f; }
    float m2 = -1e30f, l_i = 0.f;  // log2-domain running max / sum

    const int srow = lane >> 3, s3 = lane & 7;

    auto stage = [&](int buf, int c0s) {
#pragma unroll
        for (int i = 0; i < 2; ++i) {
            const int row0 = w * 16 + i * 8;                  // wave-uniform
            const int slot = s3 ^ srow ^ ((row0 >> 3) & 7);   // pre-swizzled source slot
            GLL16(Kg + (size_t)(c0s + row0 + srow) * HDIM + slot * 8, &Kl[buf][row0 * 64]);
            GLL16(Vtg + (size_t)(row0 + srow) * SEQ + c0s + slot * 8, &Vl[buf][row0 * 64]);
        }
    };

    const int rsA = (q5 & 7) ^ ((q5 >> 3) & 7);  // row swizzle for rows 0..31
    const int rsB = rsA ^ 4;                     // rows 32..63
    const int swP = (q5 >> 3) << 3;              // P group swizzle

    const float C = 0.18033688011112042f;  // 0.125 * log2(e)

    stage(0, 0);
    __syncthreads();

    for (int tile = 0; tile < SEQ / 64; ++tile) {
        const int cur = tile & 1;
        if (tile + 1 < SEQ / 64) stage(cur ^ 1, (tile + 1) * 64);

        // ---- S^T = K * Q^T ----
        f32x16 s0, s1;
#pragma unroll
        for (int e = 0; e < 16; ++e) { s0[e] = 0.f; s1[e] = 0.f; }
#pragma unroll
        for (int ks = 0; ks < 4; ++ks) {
            const int gs = 2 * ks + hi;
            const short8 k0f = *(const short8*)&Kl[cur][q5 * 64 + ((gs ^ rsA) << 3)];
            const short8 k1f =
                *(const short8*)&Kl[cur][(32 + q5) * 64 + ((gs ^ rsB) << 3)];
            s0 = __builtin_amdgcn_mfma_f32_32x32x16_bf16(k0f, qf[ks], s0, 0, 0, 0);
            s1 = __builtin_amdgcn_mfma_f32_32x32x16_bf16(k1f, qf[ks], s1, 0, 0, 0);
        }

        // ---- max (tree) over the 32 kv this lane-pair holds ----
        float a[16];
#pragma unroll
        for (int e = 0; e < 16; ++e) a[e] = fmaxf(s0[e], s1[e]);
#pragma unroll
        for (int st = 8; st >= 1; st >>= 1)
#pragma unroll
            for (int e = 0; e < 8; ++e)
                if (e < st) a[e] = fmaxf(a[e], a[e + st]);
        float mx = fmaxf(a[0], __shfl_xor(a[0], 32, 64));
        const float zmax = mx * C;

        // ---- defer-max rescale (rare) ----
        if (!__all(zmax <= m2 + 8.0f)) {
            const float m2n = fmaxf(m2, zmax);
            const float rs_ = exp2f(m2 - m2n);
            m2 = m2n;
            l_i *= rs_;
#pragma unroll
            for (int reg = 0; reg < 16; ++reg) {
                const int row = (reg & 3) + 8 * (reg >> 2) + 4 * hi;
                const float rr = __shfl(rs_, row, 64);
                oacc0[reg] *= rr;
                oacc1[reg] *= rr;
            }
        }

        // ---- P = exp2(S*C - m2), pack + write Pl, accumulate row-sum ----
        float ls = 0.f;
#pragma unroll
        for (int g = 0; g < 8; ++g) {
            const int kvsub = g >> 2, rg = g & 3;
            float pe0, pe1, pe2, pe3;
            if (kvsub == 0) {
                pe0 = exp2f(fmaf(s0[rg * 4 + 0], C, -m2));
                pe1 = exp2f(fmaf(s0[rg * 4 + 1], C, -m2));
                pe2 = exp2f(fmaf(s0[rg * 4 + 2], C, -m2));
                pe3 = exp2f(fmaf(s0[rg * 4 + 3], C, -m2));
            } else {
                pe0 = exp2f(fmaf(s1[rg * 4 + 0], C, -m2));
                pe1 = exp2f(fmaf(s1[rg * 4 + 1], C, -m2));
                pe2 = exp2f(fmaf(s1[rg * 4 + 2], C, -m2));
                pe3 = exp2f(fmaf(s1[rg * 4 + 3], C, -m2));
            }
            ls += (pe0 + pe1) + (pe2 + pe3);
            const int kv = kvsub * 32 + 8 * rg + 4 * hi;
            uint2 u;
            u.x = pk2(pe0, pe1);
            u.y = pk2(pe2, pe3);
            *(uint2*)&Pl[w][q5 * 72 + (kv ^ swP)] = u;
        }
        ls += __shfl_xor(ls, 32, 64);
        l_i += ls;

        // ---- O += P @ V  (A=P rows q, B=V^T rows d read row-contiguous) ----
#pragma unroll
        for (int ks = 0; ks < 4; ++ks) {
            const int kbase = ks * 16 + hi * 8;
            const int gs = 2 * ks + hi;
            const short8 pf = *(const short8*)&Pl[w][q5 * 72 + (kbase ^ swP)];
            const short8 v0f = *(const short8*)&Vl[cur][q5 * 64 + ((gs ^ rsA) << 3)];
            const short8 v1f =
                *(const short8*)&Vl[cur][(32 + q5) * 64 + ((gs ^ rsB) << 3)];
            oacc0 = __builtin_amdgcn_mfma_f32_32x32x16_bf16(pf, v0f, oacc0, 0, 0, 0);
            oacc1 = __builtin_amdgcn_mfma_f32_32x32x16_bf16(pf, v1f, oacc1, 0, 0, 0);
        }
        __syncthreads();
    }

    // ---- epilogue ----
    const float linv = 1.0f / l_i;
#pragma unroll
    for (int reg = 0; reg < 16; ++reg) {
        const int row = (reg & 3) + 8 * (reg >> 2) + 4 * hi;
        const float iv = __shfl(linv, row, 64);
        const int n = qt * 128 + w * 32 + row;
        float* o = Out + ((size_t)b * SEQ + n) * DIMC + h * HDIM;
        o[q5] = oacc0[reg] * iv;
        o[32 + q5] = oacc1[reg] * iv;
    }
}

extern "C" void kernel_launch(void* const* d_in, const int* in_sizes, int n_in,
                              void* d_out, int out_size, void* d_ws, size_t ws_size,
                              hipStream_t stream) {
    const float* x = (const float*)d_in[0];
    const float* wq = (const float*)d_in[1];
    const float* bias = (const float*)d_in[2];
    float* out = (float*)d_out;

    unsigned short* qkv = (unsigned short*)d_ws;                     // 25,165,824 B
    unsigned short* xb = (unsigned short*)((char*)d_ws + 25165824);  //  8,388,608 B used
    unsigned short* wT = (unsigned short*)((char*)d_ws + 41943040);  //  6,291,456 B

    cvt_fused<<<2048 + 3072, 256, 0, stream>>>(x, wq, xb, wT);
    dim3 ggrid(NCOL / 128, BATCH * SEQ / 128);
    qkv_gemm<<<ggrid, 256, 0, stream>>>(xb, wT, bias, qkv);
    attn_fwd<<<BATCH * NHEAD * (SEQ / 128), 256, 0, stream>>>(qkv, out);
}

// Round 7
// 129.707 us; speedup vs baseline: 6.5857x; 1.0068x over previous
//
#include <hip/hip_runtime.h>
#include <hip/hip_bf16.h>
#include <stdint.h>

#define DIMC 1024
#define NHEAD 16
#define HDIM 64
#define SEQ 2048
#define BATCH 2
#define NCOL 3072

typedef __attribute__((ext_vector_type(8))) short short8;
typedef __attribute__((ext_vector_type(4))) float f32x4;
typedef __attribute__((ext_vector_type(16))) float f32x16;

__device__ __forceinline__ unsigned short f2b(float f) {
    __hip_bfloat16 h = __float2bfloat16(f);
    return __builtin_bit_cast(unsigned short, h);
}
__device__ __forceinline__ unsigned int pk2(float a, float b) {
    return (unsigned int)f2b(a) | ((unsigned int)f2b(b) << 16);
}

#define GLL16(src, dst)                                                                  \
    __builtin_amdgcn_global_load_lds(                                                    \
        (const __attribute__((address_space(1))) unsigned int*)(src),                    \
        (__attribute__((address_space(3))) unsigned int*)(dst), 16, 0, 0)

// ---------------------------------------------------------------------------
// Fused converts: blocks [0,2048) do x->bf16; blocks [2048,5120) do w->wT bf16
// ---------------------------------------------------------------------------
__global__ __launch_bounds__(256) void cvt_fused(const float* __restrict__ X,
                                                 const float* __restrict__ W,
                                                 unsigned short* __restrict__ Xb,
                                                 unsigned short* __restrict__ Wt) {
    __shared__ float tile[32][33];
    const int bid = blockIdx.x;
    if (bid < 2048) {
        const int i = bid * 256 + threadIdx.x;
        const float4 a = ((const float4*)X)[2 * i];
        const float4 b = ((const float4*)X)[2 * i + 1];
        uint4 o;
        o.x = pk2(a.x, a.y);
        o.y = pk2(a.z, a.w);
        o.z = pk2(b.x, b.y);
        o.w = pk2(b.z, b.w);
        ((uint4*)Xb)[i] = o;
    } else {
        const int b2 = bid - 2048;
        const int k0 = (b2 & 31) * 32, n0 = (b2 >> 5) * 32;
        const int r = threadIdx.x >> 3, c4 = (threadIdx.x & 7) * 4;
        *(float4*)&tile[r][c4] = *(const float4*)&W[(size_t)(k0 + r) * NCOL + n0 + c4];
        __syncthreads();
        uint2 o;
        o.x = pk2(tile[c4 + 0][r], tile[c4 + 1][r]);
        o.y = pk2(tile[c4 + 2][r], tile[c4 + 3][r]);
        *(uint2*)&Wt[(size_t)(n0 + r) * DIMC + k0 + c4] = o;
    }
}

// ---------------------------------------------------------------------------
// qkv GEMM. Q,K written [which][b][h][n][d]; V written TRANSPOSED [b][h][d][n]
// into the V region (offset 2*B*H*N*D), packed 8B stores.  (unchanged, proven)
// ---------------------------------------------------------------------------
__global__ __launch_bounds__(256) void qkv_gemm(const unsigned short* __restrict__ Xb,
                                                const unsigned short* __restrict__ Wt,
                                                const float* __restrict__ Bias,
                                                unsigned short* __restrict__ QKV) {
    __shared__ short Al[128 * 64];
    __shared__ short Bl[128 * 64];
    const int t = threadIdx.x;
    const int lane = t & 63;
    const int w = t >> 6;
    const int m0 = blockIdx.y * 128, n0 = blockIdx.x * 128;
    const int wr = w >> 1, wc = w & 1;

    f32x4 acc[4][4];
#pragma unroll
    for (int i = 0; i < 4; ++i)
#pragma unroll
        for (int j = 0; j < 4; ++j)
#pragma unroll
            for (int e = 0; e < 4; ++e) acc[i][j][e] = 0.f;

    const int srow = lane >> 3;
    const int sslot = (lane & 7) ^ srow;

    for (int k0 = 0; k0 < DIMC; k0 += 64) {
        __syncthreads();
#pragma unroll
        for (int i = 0; i < 4; ++i) {
            const int row = w * 32 + i * 8;
            GLL16(Xb + (size_t)(m0 + row + srow) * DIMC + k0 + sslot * 8, &Al[row * 64]);
            GLL16(Wt + (size_t)(n0 + row + srow) * DIMC + k0 + sslot * 8, &Bl[row * 64]);
        }
        __syncthreads();
#pragma unroll
        for (int kb = 0; kb < 2; ++kb) {
            short8 af[4], bfr[4];
#pragma unroll
            for (int rf = 0; rf < 4; ++rf) {
                const int mloc = wr * 64 + rf * 16 + (lane & 15);
                const int slot = (4 * kb + (lane >> 4)) ^ (mloc & 7);
                af[rf] = *(const short8*)&Al[mloc * 64 + slot * 8];
            }
#pragma unroll
            for (int cf = 0; cf < 4; ++cf) {
                const int nloc = wc * 64 + cf * 16 + (lane & 15);
                const int slot = (4 * kb + (lane >> 4)) ^ (nloc & 7);
                bfr[cf] = *(const short8*)&Bl[nloc * 64 + slot * 8];
            }
#pragma unroll
            for (int rf = 0; rf < 4; ++rf)
#pragma unroll
                for (int cf = 0; cf < 4; ++cf)
                    acc[rf][cf] = __builtin_amdgcn_mfma_f32_16x16x32_bf16(
                        af[rf], bfr[cf], acc[rf][cf], 0, 0, 0);
        }
    }

    float bias_c[4];
    int j0_c[4];
#pragma unroll
    for (int cf = 0; cf < 4; ++cf) {
        j0_c[cf] = n0 + wc * 64 + cf * 16 + (lane & 15);
        bias_c[cf] = Bias[j0_c[cf]];
    }

    const int whichU = n0 >> 10;  // uniform per block
    if (whichU < 2) {
#pragma unroll
        for (int rf = 0; rf < 4; ++rf) {
#pragma unroll
            for (int r = 0; r < 4; ++r) {
                const int m = m0 + wr * 64 + rf * 16 + (lane >> 4) * 4 + r;
                const int bb = m >> 11, nn = m & (SEQ - 1);
#pragma unroll
                for (int cf = 0; cf < 4; ++cf) {
                    const int j0 = j0_c[cf];
                    const int h = (j0 >> 6) & 15, d = j0 & 63;
                    QKV[(size_t)(((whichU * BATCH + bb) * NHEAD + h) * SEQ + nn) * HDIM +
                        d] = f2b(acc[rf][cf][r] + bias_c[cf]);
                }
            }
        }
    } else {
        const int bb = m0 >> 11;
        const size_t vbase = (size_t)2 * BATCH * NHEAD * SEQ * HDIM;
#pragma unroll
        for (int rf = 0; rf < 4; ++rf) {
            const int nn = (m0 & (SEQ - 1)) + wr * 64 + rf * 16 + (lane >> 4) * 4;
#pragma unroll
            for (int cf = 0; cf < 4; ++cf) {
                const int j0 = j0_c[cf];
                const int h = (j0 >> 6) & 15, d = j0 & 63;
                uint2 u;
                u.x = pk2(acc[rf][cf][0] + bias_c[cf], acc[rf][cf][1] + bias_c[cf]);
                u.y = pk2(acc[rf][cf][2] + bias_c[cf], acc[rf][cf][3] + bias_c[cf]);
                *(uint2*)&QKV[vbase + (((size_t)bb * NHEAD + h) * HDIM + d) * SEQ + nn] = u;
            }
        }
    }
}

// ---------------------------------------------------------------------------
// Flash attention v4: v3 + register-exchange P path (no P LDS), XCD-affinity
// block decode, setprio around MFMA.
// ---------------------------------------------------------------------------
__global__ __launch_bounds__(256) void attn_fwd(const unsigned short* __restrict__ QKV,
                                                float* __restrict__ Out) {
    __shared__ short Kl[2][64 * 64];   // [kv][d], slot s of row r holds global slot s^rs(r)
    __shared__ short Vl[2][64 * 64];   // [d][kv], same swizzle

    const int t = threadIdx.x;
    const int lane = t & 63;
    const int w = t >> 6;
    const int hi = lane >> 5;
    const int q5 = lane & 31;

    // XCD-affinity: all 16 q-tile blocks of one (b,h) share bid%32 -> same XCD
    const int bh = blockIdx.x & 31;
    const int qt = blockIdx.x >> 5;
    const int b = bh >> 4, h = bh & 15;

    const size_t plane = (size_t)SEQ * HDIM;
    const unsigned short* Qg = QKV + ((size_t)(0 * BATCH + b) * NHEAD + h) * plane;
    const unsigned short* Kg = QKV + ((size_t)(1 * BATCH + b) * NHEAD + h) * plane;
    const unsigned short* Vtg =
        QKV + (size_t)2 * BATCH * NHEAD * plane + ((size_t)(b * NHEAD + h)) * plane;

    // Q fragment (B operand of S^T = K*Q^T): col=q5, k = ks*16 + hi*8 + j
    const int qrow = qt * 128 + w * 32 + q5;
    short8 qf[4];
#pragma unroll
    for (int ks = 0; ks < 4; ++ks)
        qf[ks] = *(const short8*)&Qg[(size_t)qrow * HDIM + ks * 16 + hi * 8];

    f32x16 oacc0, oacc1;
#pragma unroll
    for (int e = 0; e < 16; ++e) { oacc0[e] = 0.f; oacc1[e] = 0.f; }
    float m2 = -1e30f, l_i = 0.f;  // log2-domain running max / sum

    const int srow = lane >> 3, s3 = lane & 7;

    auto stage = [&](int buf, int c0s) {
#pragma unroll
        for (int i = 0; i < 2; ++i) {
            const int row0 = w * 16 + i * 8;                  // wave-uniform
            const int slot = s3 ^ srow ^ ((row0 >> 3) & 7);   // pre-swizzled source slot
            GLL16(Kg + (size_t)(c0s + row0 + srow) * HDIM + slot * 8, &Kl[buf][row0 * 64]);
            GLL16(Vtg + (size_t)(row0 + srow) * SEQ + c0s + slot * 8, &Vl[buf][row0 * 64]);
        }
    };

    const int rsA = (q5 & 7) ^ ((q5 >> 3) & 7);  // row swizzle for rows 0..31
    const int rsB = rsA ^ 4;                     // rows 32..63

    const float C = 0.18033688011112042f;  // 0.125 * log2(e)

    stage(0, 0);
    __syncthreads();

    for (int tile = 0; tile < SEQ / 64; ++tile) {
        const int cur = tile & 1;
        if (tile + 1 < SEQ / 64) stage(cur ^ 1, (tile + 1) * 64);

        // ---- S^T = K * Q^T ----
        f32x16 s0, s1;
#pragma unroll
        for (int e = 0; e < 16; ++e) { s0[e] = 0.f; s1[e] = 0.f; }
#pragma unroll
        for (int ks = 0; ks < 4; ++ks) {
            const int gs = 2 * ks + hi;
            const short8 k0f = *(const short8*)&Kl[cur][q5 * 64 + ((gs ^ rsA) << 3)];
            const short8 k1f =
                *(const short8*)&Kl[cur][(32 + q5) * 64 + ((gs ^ rsB) << 3)];
            __builtin_amdgcn_s_setprio(1);
            s0 = __builtin_amdgcn_mfma_f32_32x32x16_bf16(k0f, qf[ks], s0, 0, 0, 0);
            s1 = __builtin_amdgcn_mfma_f32_32x32x16_bf16(k1f, qf[ks], s1, 0, 0, 0);
            __builtin_amdgcn_s_setprio(0);
        }

        // ---- max over the 32 kv this lane-pair holds (max3-friendly tree) ----
        float a[8];
#pragma unroll
        for (int e = 0; e < 8; ++e)
            a[e] = fmaxf(fmaxf(s0[2 * e], s0[2 * e + 1]),
                         fmaxf(s1[2 * e], s1[2 * e + 1]));
        const float r0m = fmaxf(fmaxf(a[0], a[1]), a[2]);
        const float r1m = fmaxf(fmaxf(a[3], a[4]), a[5]);
        const float r2m = fmaxf(fmaxf(a[6], a[7]), r0m);
        float mx = fmaxf(r1m, r2m);
        mx = fmaxf(mx, __shfl_xor(mx, 32, 64));
        const float zmax = mx * C;

        // ---- defer-max rescale (rare) ----
        if (!__all(zmax <= m2 + 8.0f)) {
            const float m2n = fmaxf(m2, zmax);
            const float rs_ = exp2f(m2 - m2n);
            m2 = m2n;
            l_i *= rs_;
#pragma unroll
            for (int reg = 0; reg < 16; ++reg) {
                const int row = (reg & 3) + 8 * (reg >> 2) + 4 * hi;
                const float rr = __shfl(rs_, row, 64);
                oacc0[reg] *= rr;
                oacc1[reg] *= rr;
            }
        }

        // ---- P = exp2(S*C - m2), pack to bf16 words in registers ----
        float ls = 0.f;
        unsigned int W0[8], W1[8];
#pragma unroll
        for (int e = 0; e < 16; ++e) {
            s0[e] = exp2f(fmaf(s0[e], C, -m2));
            ls += s0[e];
        }
#pragma unroll
        for (int e = 0; e < 16; ++e) {
            s1[e] = exp2f(fmaf(s1[e], C, -m2));
            ls += s1[e];
        }
#pragma unroll
        for (int j = 0; j < 8; ++j) {
            W0[j] = pk2(s0[2 * j], s0[2 * j + 1]);   // quad m=j>>1: kv 8m+4hi+{0..3}
            W1[j] = pk2(s1[2 * j], s1[2 * j + 1]);   // +32
        }
        ls += __shfl_xor(ls, 32, 64);
        l_i += ls;

        // ---- O += P @ V: A-fragment built by lane-pair quad exchange (T12) ----
        // Per ks: self quad m=(2ks+hi)&3, partner quad via 2 shfl_xor(32).
#pragma unroll
        for (int ks = 0; ks < 4; ++ks) {
            const int base = (ks & 1) * 4;
            unsigned int u, u2, p, p2;
            if (ks < 2) {
                u = W0[base + 0]; u2 = W0[base + 1];
                p = W0[base + 2]; p2 = W0[base + 3];
            } else {
                u = W1[base + 0]; u2 = W1[base + 1];
                p = W1[base + 2]; p2 = W1[base + 3];
            }
            const unsigned int E0 = hi ? u : p;
            const unsigned int E1 = hi ? u2 : p2;
            const unsigned int r0 = __shfl_xor(E0, 32, 64);
            const unsigned int r1 = __shfl_xor(E1, 32, 64);
            uint4 pw;
            pw.x = hi ? r0 : u;
            pw.y = hi ? r1 : u2;
            pw.z = hi ? p : r0;
            pw.w = hi ? p2 : r1;
            const short8 pf = __builtin_bit_cast(short8, pw);

            const int gs = 2 * ks + hi;
            const short8 v0f = *(const short8*)&Vl[cur][q5 * 64 + ((gs ^ rsA) << 3)];
            const short8 v1f =
                *(const short8*)&Vl[cur][(32 + q5) * 64 + ((gs ^ rsB) << 3)];
            __builtin_amdgcn_s_setprio(1);
            oacc0 = __builtin_amdgcn_mfma_f32_32x32x16_bf16(pf, v0f, oacc0, 0, 0, 0);
            oacc1 = __builtin_amdgcn_mfma_f32_32x32x16_bf16(pf, v1f, oacc1, 0, 0, 0);
            __builtin_amdgcn_s_setprio(0);
        }
        __syncthreads();
    }

    // ---- epilogue ----
    const float linv = 1.0f / l_i;
#pragma unroll
    for (int reg = 0; reg < 16; ++reg) {
        const int row = (reg & 3) + 8 * (reg >> 2) + 4 * hi;
        const float iv = __shfl(linv, row, 64);
        const int n = qt * 128 + w * 32 + row;
        float* o = Out + ((size_t)b * SEQ + n) * DIMC + h * HDIM;
        o[q5] = oacc0[reg] * iv;
        o[32 + q5] = oacc1[reg] * iv;
    }
}

extern "C" void kernel_launch(void* const* d_in, const int* in_sizes, int n_in,
                              void* d_out, int out_size, void* d_ws, size_t ws_size,
                              hipStream_t stream) {
    const float* x = (const float*)d_in[0];
    const float* wq = (const float*)d_in[1];
    const float* bias = (const float*)d_in[2];
    float* out = (float*)d_out;

    unsigned short* qkv = (unsigned short*)d_ws;                     // 25,165,824 B
    unsigned short* xb = (unsigned short*)((char*)d_ws + 25165824);  //  8,388,608 B used
    unsigned short* wT = (unsigned short*)((char*)d_ws + 41943040);  //  6,291,456 B

    cvt_fused<<<2048 + 3072, 256, 0, stream>>>(x, wq, xb, wT);
    dim3 ggrid(NCOL / 128, BATCH * SEQ / 128);
    qkv_gemm<<<ggrid, 256, 0, stream>>>(xb, wT, bias, qkv);
    attn_fwd<<<BATCH * NHEAD * (SEQ / 128), 256, 0, stream>>>(qkv, out);
}